// Round 20
// baseline (387.001 us; speedup 1.0000x reference)
//
#include <hip/hip_runtime.h>
#include <math.h>

typedef unsigned short u16;
typedef short s16x8 __attribute__((ext_vector_type(8)));
typedef float f32x4 __attribute__((ext_vector_type(4)));

#define MFMA16(a, b, c) __builtin_amdgcn_mfma_f32_16x16x32_bf16((a), (b), (c), 0, 0, 0)

__device__ __forceinline__ u16 f2b(float f) {
  unsigned u = __float_as_uint(f);
  unsigned r = (u + 0x7fff + ((u >> 16) & 1)) >> 16;
  return (u16)r;
}
__device__ __forceinline__ float b2f(u16 h) { return __uint_as_float(((unsigned)h) << 16); }

// ---------------- fused prep: LayerNorm + both weight transposes + scal init ----------------
__global__ __launch_bounds__(256) void prep_kernel(const float* __restrict__ x, const float* __restrict__ w,
    const float* __restrict__ b, u16* __restrict__ xn,
    const float* __restrict__ Wq, u16* __restrict__ WqT,
    const float* __restrict__ Wo, u16* __restrict__ WoT,
    unsigned* __restrict__ scal) {
  int bI = blockIdx.x;
  int t = threadIdx.x;
  if (bI == 0 && t == 0) { scal[0] = 0u; scal[1] = 0u; }
  if (bI < 16384) {
    int row = bI;
    const float* xr = x + (size_t)row * 512;
    float v0 = xr[t], v1 = xr[t + 256];
    float s = v0 + v1, ss = v0*v0 + v1*v1;
    for (int o = 32; o > 0; o >>= 1) { s += __shfl_down(s, o); ss += __shfl_down(ss, o); }
    __shared__ float ls[4], lss[4];
    int wid = t >> 6, lane = t & 63;
    if (lane == 0) { ls[wid] = s; lss[wid] = ss; }
    __syncthreads();
    float tot  = ls[0]+ls[1]+ls[2]+ls[3];
    float tot2 = lss[0]+lss[1]+lss[2]+lss[3];
    float mean = tot * (1.f/512);
    float var  = tot2 * (1.f/512) - mean*mean;
    float inv = rsqrtf(var + 1e-5f);
    u16* xo = xn + (size_t)row * 512;
    xo[t]     = f2b((v0-mean)*inv*w[t]     + b[t]);
    xo[t+256] = f2b((v1-mean)*inv*w[t+256] + b[t+256]);
  } else if (bI < 16384 + 3072) {
    int idx = (bI - 16384)*256 + t;
    int r = idx / 1536, c = idx - r*1536;
    WqT[(size_t)c*512 + r] = f2b(Wq[idx]);
  } else {
    int idx = (bI - 19456)*256 + t;
    int r = idx >> 9, c = idx & 511;
    WoT[(size_t)c*512 + r] = f2b(Wo[idx]);
  }
}

// ---------------- 128x128 MFMA GEMM core, BK=32 + 1-deep register prefetch (proven) ----------------
__device__ __forceinline__ void gemm128_pf(const u16* __restrict__ A, const u16* __restrict__ BT,
    int K, int ldA, int ldBT, int row0, int col0, u16* As, u16* Bs, f32x4 acc[4][4]) {
  int t = threadIdx.x, lane = t & 63, wid = t >> 6;
  int wr = (wid >> 1) * 64, wc = (wid & 1) * 64;
  int lr = lane & 15, lg = lane >> 4;
  int sr = t >> 2, sc = (t & 3) * 8;
  const u16* Ar0 = A  + (size_t)(row0 + sr)*ldA + sc;
  const u16* Ar1 = A  + (size_t)(row0 + sr + 64)*ldA + sc;
  const u16* Br0 = BT + (size_t)(col0 + sr)*ldBT + sc;
  const u16* Br1 = BT + (size_t)(col0 + sr + 64)*ldBT + sc;
  uint4 pa0 = *(const uint4*)Ar0, pa1 = *(const uint4*)Ar1;
  uint4 pb0 = *(const uint4*)Br0, pb1 = *(const uint4*)Br1;
  for (int k0 = 0; k0 < K; k0 += 32) {
    __syncthreads();
    *(uint4*)&As[sr*40 + sc]        = pa0;
    *(uint4*)&As[(sr + 64)*40 + sc] = pa1;
    *(uint4*)&Bs[sr*40 + sc]        = pb0;
    *(uint4*)&Bs[(sr + 64)*40 + sc] = pb1;
    __syncthreads();
    if (k0 + 32 < K) {
      pa0 = *(const uint4*)(Ar0 + k0 + 32);
      pa1 = *(const uint4*)(Ar1 + k0 + 32);
      pb0 = *(const uint4*)(Br0 + k0 + 32);
      pb1 = *(const uint4*)(Br1 + k0 + 32);
    }
    s16x8 af[4], bf[4];
    #pragma unroll
    for (int f = 0; f < 4; f++) {
      af[f] = *(s16x8*)&As[(wr + f*16 + lr)*40 + lg*8];
      bf[f] = *(s16x8*)&Bs[(wc + f*16 + lr)*40 + lg*8];
    }
    #pragma unroll
    for (int i = 0; i < 4; i++)
      #pragma unroll
      for (int j = 0; j < 4; j++)
        acc[i][j] = MFMA16(af[i], bf[j], acc[i][j]);
  }
}

// ---------------- 64x64 MFMA GEMM core (K=256), BK=64 + register prefetch (proven) ----------------
__device__ __forceinline__ void gemm64_pf(const u16* __restrict__ Ab, const u16* __restrict__ Bb,
    int row0, int col0, u16* As, u16* Bs, f32x4 acc[2][2]) {
  int t = threadIdx.x, lane = t & 63, wid = t >> 6;
  int wr = (wid >> 1)*32, wc = (wid & 1)*32;
  int lr = lane & 15, lg = lane >> 4;
  int sr = t >> 3, sc = (t & 7)*8;
  const u16* Ar0 = Ab + (size_t)(row0 + sr)*256 + sc;
  const u16* Ar1 = Ab + (size_t)(row0 + 32 + sr)*256 + sc;
  const u16* Br0 = Bb + (size_t)(col0 + sr)*256 + sc;
  const u16* Br1 = Bb + (size_t)(col0 + 32 + sr)*256 + sc;
  uint4 pa0 = *(const uint4*)Ar0, pa1 = *(const uint4*)Ar1;
  uint4 pb0 = *(const uint4*)Br0, pb1 = *(const uint4*)Br1;
  for (int k0 = 0; k0 < 256; k0 += 64) {
    __syncthreads();
    *(uint4*)&As[sr*72 + sc]        = pa0;
    *(uint4*)&As[(sr + 32)*72 + sc] = pa1;
    *(uint4*)&Bs[sr*72 + sc]        = pb0;
    *(uint4*)&Bs[(sr + 32)*72 + sc] = pb1;
    __syncthreads();
    if (k0 + 64 < 256) {
      pa0 = *(const uint4*)(Ar0 + k0 + 64);
      pa1 = *(const uint4*)(Ar1 + k0 + 64);
      pb0 = *(const uint4*)(Br0 + k0 + 64);
      pb1 = *(const uint4*)(Br1 + k0 + 64);
    }
    #pragma unroll
    for (int kk = 0; kk < 2; kk++) {
      s16x8 af[2], bf[2];
      #pragma unroll
      for (int f = 0; f < 2; f++) {
        af[f] = *(s16x8*)&As[(wr + f*16 + lr)*72 + kk*32 + lg*8];
        bf[f] = *(s16x8*)&Bs[(wc + f*16 + lr)*72 + kk*32 + lg*8];
      }
      #pragma unroll
      for (int i = 0; i < 2; i++)
        #pragma unroll
        for (int j = 0; j < 2; j++)
          acc[i][j] = MFMA16(af[i], bf[j], acc[i][j]);
    }
  }
}

// ---------------- QKV (XCD-swizzled) + fused landmarks ----------------
__global__ __launch_bounds__(256, 4) void qkv_mfma(const u16* __restrict__ xn, const u16* __restrict__ wT,
    u16* __restrict__ q, u16* __restrict__ k, u16* __restrict__ v,
    u16* __restrict__ ql, u16* __restrict__ kl) {
  __shared__ u16 As[128*40], Bs[128*40];
  f32x4 acc[4][4];
  #pragma unroll
  for (int i = 0; i < 4; i++)
    #pragma unroll
    for (int j = 0; j < 4; j++) acc[i][j] = (f32x4)0.f;
  int bI = blockIdx.x;
  int job = (bI & 7)*192 + (bI >> 3);
  int row0 = (job / 12) * 128, col0 = (job % 12) * 128;
  gemm128_pf(xn, wT, 512, 512, 512, row0, col0, As, Bs, acc);
  int t = threadIdx.x, lane = t & 63, wid = t >> 6, lr = lane & 15, lg = lane >> 4;
  int wr = (wid >> 1)*64, wc = (wid & 1)*64;
  int part = col0 >> 9;
  #pragma unroll
  for (int i = 0; i < 4; i++)
    #pragma unroll
    for (int j = 0; j < 4; j++)
      #pragma unroll
      for (int r = 0; r < 4; r++) {
        int row = row0 + wr + i*16 + lg*4 + r;
        int col = col0 + wc + j*16 + lr;
        float val = acc[i][j][r];
        int rem = col & 511, h = rem >> 6, d = rem & 63;
        int b = row >> 12, n = row & 4095;
        size_t bh = (size_t)(b*8 + h);
        size_t dst = (bh*4096 + n)*64 + d;
        if (part == 0)      q[dst] = f2b(val * 0.125f);
        else if (part == 1) k[dst] = f2b(val);
        else                v[dst] = f2b(val);
      }
  if (part <= 1) {
    #pragma unroll
    for (int i = 0; i < 4; i++) {
      #pragma unroll
      for (int j = 0; j < 4; j++) {
        float s = acc[i][j][0] + acc[i][j][1] + acc[i][j][2] + acc[i][j][3];
        s += __shfl_xor(s, 16);
        s += __shfl_xor(s, 32);
        if (lg == 0) {
          int row16 = row0 + wr + i*16;
          int b = row16 >> 12, n = row16 & 4095;
          int m = n >> 4;
          int col = col0 + wc + j*16 + lr;
          int rem = col & 511, h = rem >> 6, d = rem & 63;
          size_t dst = ((size_t)(b*8 + h)*256 + m)*64 + d;
          if (part == 0) ql[dst] = f2b(s * (0.125f/16.f));
          else           kl[dst] = f2b(s * (1.f/16.f));
        }
      }
    }
  }
}

// ---------------- out GEMM (XCD-swizzled) ----------------
__global__ __launch_bounds__(256, 4) void out_mfma(const u16* __restrict__ outh, const u16* __restrict__ wT,
    const float* __restrict__ bo, const float* __restrict__ x, float* __restrict__ out) {
  __shared__ u16 As[128*40], Bs[128*40];
  f32x4 acc[4][4];
  #pragma unroll
  for (int i = 0; i < 4; i++)
    #pragma unroll
    for (int j = 0; j < 4; j++) acc[i][j] = (f32x4)0.f;
  int bI = blockIdx.x;
  int job = (bI & 7)*64 + (bI >> 3);
  int row0 = (job / 4) * 128, col0 = (job % 4) * 128;
  gemm128_pf(outh, wT, 512, 512, 512, row0, col0, As, Bs, acc);
  int t = threadIdx.x, lane = t & 63, wid = t >> 6, lr = lane & 15, lg = lane >> 4;
  int wr = (wid >> 1)*64, wc = (wid & 1)*64;
  #pragma unroll
  for (int i = 0; i < 4; i++)
    #pragma unroll
    for (int j = 0; j < 4; j++)
      #pragma unroll
      for (int r = 0; r < 4; r++) {
        int row = row0 + wr + i*16 + lg*4 + r;
        int col = col0 + wc + j*16 + lr;
        size_t idx = (size_t)row*512 + col;
        out[idx] = x[idx] + acc[i][j][r] + bo[col];
      }
}

// ---------------- fused mid: sim2(+a2hT) (128) + vtrans (2048) + conv->outh (1024) ----------------
__global__ __launch_bounds__(256) void mid_kernel(
    const u16* __restrict__ v, u16* __restrict__ vT,
    const u16* __restrict__ ql, const u16* __restrict__ kl,
    u16* __restrict__ a2h, u16* __restrict__ a2hT, float* __restrict__ pcs,
    const float* __restrict__ rw, u16* __restrict__ outh) {
  __shared__ __align__(16) u16 smem[25600];
  int bI = blockIdx.x;
  int t = threadIdx.x;
  if (bI < 128) {
    int rq = bI & 3, bh = bI >> 2;
    u16* Qs  = smem;
    u16* Ks2 = smem + 4608;
    u16* Pt  = smem;                       // overlays Qs/Ks2 after MFMA phase (256*72)
    float* wcol = (float*)(smem + 23040);
    int lane = t & 63, wid = t >> 6, lr = lane & 15, lg = lane >> 4;
    #pragma unroll
    for (int p = 0; p < 2; p++) {
      int c = t + p*256;
      int r = c >> 3, col = (c & 7)*8;
      *(uint4*)&Qs[r*72 + col] = *(const uint4*)&ql[((size_t)bh*256 + rq*64 + r)*64 + col];
    }
    #pragma unroll
    for (int p = 0; p < 8; p++) {
      int c = t + p*256;
      int r = c >> 3, col = (c & 7)*8;
      *(uint4*)&Ks2[r*72 + col] = *(const uint4*)&kl[((size_t)bh*256 + r)*64 + col];
    }
    __syncthreads();
    float colp[16];
    #pragma unroll
    for (int cf = 0; cf < 16; cf++) colp[cf] = 0.f;
    int rbase = wid*16;
    s16x8 a0 = *(s16x8*)&Qs[(rbase + lr)*72 + lg*8];
    s16x8 a1 = *(s16x8*)&Qs[(rbase + lr)*72 + 32 + lg*8];
    f32x4 sf[16];
    #pragma unroll
    for (int cf = 0; cf < 16; cf++) {
      s16x8 b0 = *(s16x8*)&Ks2[(cf*16 + lr)*72 + lg*8];
      s16x8 b1 = *(s16x8*)&Ks2[(cf*16 + lr)*72 + 32 + lg*8];
      sf[cf] = MFMA16(a1, b1, MFMA16(a0, b0, (f32x4)0.f));
    }
    float invs[4];
    #pragma unroll
    for (int r = 0; r < 4; r++) {
      float mx = -3e38f;
      #pragma unroll
      for (int cf = 0; cf < 16; cf++) mx = fmaxf(mx, sf[cf][r]);
      #pragma unroll
      for (int o = 1; o < 16; o <<= 1) mx = fmaxf(mx, __shfl_xor(mx, o));
      float sum = 0.f;
      #pragma unroll
      for (int cf = 0; cf < 16; cf++) { sf[cf][r] = __expf(sf[cf][r] - mx); sum += sf[cf][r]; }
      #pragma unroll
      for (int o = 1; o < 16; o <<= 1) sum += __shfl_xor(sum, o);
      float inv = 1.f / sum;
      invs[r] = inv;
      int row = rq*64 + rbase + lg*4 + r;
      size_t base = (size_t)bh*65536 + (size_t)row*256;
      #pragma unroll
      for (int cf = 0; cf < 16; cf++) {
        float pp = sf[cf][r] * inv;
        a2h[base + cf*16 + lr] = f2b(pp);
        colp[cf] += pp;
      }
    }
    #pragma unroll
    for (int cf = 0; cf < 16; cf++) {
      colp[cf] += __shfl_xor(colp[cf], 16);
      colp[cf] += __shfl_xor(colp[cf], 32);
    }
    if (lg == 0) {
      #pragma unroll
      for (int cf = 0; cf < 16; cf++) wcol[wid*256 + cf*16 + lr] = colp[cf];
    }
    __syncthreads();   // all MFMA/Ks2 reads done; wcol ready
    pcs[((size_t)bh*4 + rq)*256 + t] = wcol[t] + wcol[256 + t] + wcol[512 + t] + wcol[768 + t];
    // write transposed P into Pt (overlays Qs/Ks2): Pt[col*72 + localrow]
    #pragma unroll
    for (int cf = 0; cf < 16; cf++) {
      int col = cf*16 + lr;
      #pragma unroll
      for (int r = 0; r < 4; r++) {
        int lrow = rbase + lg*4 + r;
        Pt[col*72 + lrow] = f2b(sf[cf][r] * invs[r]);
      }
    }
    __syncthreads();
    // flush Pt -> a2hT[bh][j][rq*64 + i], coalesced 16B stores
    #pragma unroll
    for (int p = 0; p < 8; p++) {
      int c = t + p*256;           // 2048 uint4 chunks = 256 cols x 8
      int j = c >> 3, o8 = (c & 7)*8;
      *(uint4*)&a2hT[(size_t)bh*65536 + (size_t)j*256 + rq*64 + o8] = *(uint4*)&Pt[j*72 + o8];
    }
  } else if (bI < 2176) {
    int idx = bI - 128;
    int bh = idx >> 6, n0 = (idx & 63) * 64;
    u16* tile = smem;
    const u16* vb = v + ((size_t)bh*4096 + n0)*64;
    #pragma unroll
    for (int p = 0; p < 2; p++) {
      int c = t + p*256;
      int r = c >> 3, col = (c & 7)*8;
      *(uint4*)&tile[r*72 + col] = *(const uint4*)&vb[(size_t)r*64 + col];
    }
    __syncthreads();
    #pragma unroll
    for (int p = 0; p < 2; p++) {
      int c = t + p*256;
      int d = c >> 3, ncol = (c & 7)*8;
      u16 tmp[8];
      #pragma unroll
      for (int j = 0; j < 8; j++) tmp[j] = tile[(ncol + j)*72 + d];
      *(uint4*)&vT[((size_t)bh*64 + d)*4096 + n0 + ncol] = *(uint4*)tmp;
    }
  } else {
    int idx = bI - 2176;
    int bh = idx >> 5, n0 = (idx & 31) * 128;
    int b = bh >> 3, h = bh & 7;
    u16* tile = smem;
    float* wsm = (float*)(smem + 11520);
    if (t < 33) wsm[t] = rw[h*33 + t];
    const u16* vb = v + ((size_t)bh*4096)*64;
    #pragma unroll
    for (int p = 0; p < 5; p++) {
      int c = t + p*256;
      int r = c >> 3, col = (c & 7)*8;
      int nn = n0 - 16 + r;
      uint4 val = make_uint4(0u,0u,0u,0u);
      if (nn >= 0 && nn < 4096) val = *(const uint4*)&vb[(size_t)nn*64 + col];
      *(uint4*)&tile[r*72 + col] = val;
    }
    __syncthreads();
    int d8 = (t & 7) * 8;
    int r0 = t >> 3;
    #pragma unroll
    for (int pass = 0; pass < 4; pass++) {
      int lrow = pass*32 + r0;
      float acc[8] = {};
      #pragma unroll
      for (int j = 0; j < 33; j++) {
        uint4 vv = *(uint4*)&tile[(lrow + j)*72 + d8];
        float w = wsm[j];
        acc[0] += b2f((u16)(vv.x & 0xffff)) * w;
        acc[1] += b2f((u16)(vv.x >> 16))    * w;
        acc[2] += b2f((u16)(vv.y & 0xffff)) * w;
        acc[3] += b2f((u16)(vv.y >> 16))    * w;
        acc[4] += b2f((u16)(vv.z & 0xffff)) * w;
        acc[5] += b2f((u16)(vv.z >> 16))    * w;
        acc[6] += b2f((u16)(vv.w & 0xffff)) * w;
        acc[7] += b2f((u16)(vv.w >> 16))    * w;
      }
      size_t oi = ((size_t)(b*4096 + n0 + lrow))*512 + h*64 + d8;
      uint4 nv;
      nv.x = (unsigned)f2b(acc[0]) | ((unsigned)f2b(acc[1]) << 16);
      nv.y = (unsigned)f2b(acc[2]) | ((unsigned)f2b(acc[3]) << 16);
      nv.z = (unsigned)f2b(acc[4]) | ((unsigned)f2b(acc[5]) << 16);
      nv.w = (unsigned)f2b(acc[6]) | ((unsigned)f2b(acc[7]) << 16);
      *(uint4*)&outh[oi] = nv;
    }
  }
}

// ---------------- colmax ----------------
__global__ __launch_bounds__(256) void colmax_kernel(const float* __restrict__ pcs, unsigned* __restrict__ scal) {
  __shared__ float red[256];
  int bh = blockIdx.x, t = threadIdx.x;
  size_t b4 = (size_t)bh*4*256;
  red[t] = pcs[b4 + t] + pcs[b4 + 256 + t] + pcs[b4 + 512 + t] + pcs[b4 + 768 + t];
  __syncthreads();
  for (int o = 128; o > 0; o >>= 1) {
    if (t < o) red[t] = fmaxf(red[t], red[t+o]);
    __syncthreads();
  }
  if (t == 0) atomicMax(scal + 1, __float_as_uint(red[0]));
}

// ---------------- device bodies for fused pinv_s1 launches ----------------
__device__ __forceinline__ void s1_body(int bI, u16* As, u16* Bs,
    const u16* __restrict__ a2h, const u16* __restrict__ zcT,
    u16* __restrict__ xz, u16* __restrict__ xzT, u16* __restrict__ e1T, float sc) {
  size_t bb = (size_t)(bI >> 4) << 16;
  int row0 = ((bI >> 2) & 3)*64, col0 = (bI & 3)*64;
  f32x4 acc[2][2];
  #pragma unroll
  for (int i = 0; i < 2; i++) { acc[i][0] = (f32x4)0.f; acc[i][1] = (f32x4)0.f; }
  gemm64_pf(a2h + bb, zcT + bb, row0, col0, As, Bs, acc);
  int t = threadIdx.x, lane = t & 63, wid = t >> 6, lr = lane & 15, lg = lane >> 4;
  int wr = (wid >> 1)*32, wc = (wid & 1)*32;
  #pragma unroll
  for (int i = 0; i < 2; i++)
    #pragma unroll
    for (int j = 0; j < 2; j++)
      #pragma unroll
      for (int r = 0; r < 4; r++) {
        int row = row0 + wr + i*16 + lg*4 + r;
        int col = col0 + wc + j*16 + lr;
        float c = acc[i][j][r] * sc;
        xz [bb + (size_t)row*256 + col] = f2b(c);
        xzT[bb + (size_t)col*256 + row] = f2b(c);
        e1T[bb + (size_t)col*256 + row] = f2b((row == col ? 7.f : 0.f) - c);
      }
}

__device__ __forceinline__ void flash_body(int f, u16* smem,
    const u16* __restrict__ Q, const u16* __restrict__ Kg, const u16* __restrict__ VT,
    u16* __restrict__ po, float* __restrict__ pl) {
  u16* Ks = smem;
  u16* Vs = smem + 4608;
  u16* Ps = smem + 9216;
  int t = threadIdx.x;
  int ch = f & 7, qg = (f >> 3) & 1, bh = f >> 4;
  int lane = t & 63, wid = t >> 6, lr = lane & 15, lg = lane >> 4;
  const u16* Qb  = Q  + ((size_t)bh*256)*64;
  const u16* Kb  = Kg + ((size_t)bh*4096 + ch*512)*64;
  const u16* VTb = VT + ((size_t)bh*64)*4096 + ch*512;
  s16x8 aq[2][2];
  #pragma unroll
  for (int qq = 0; qq < 2; qq++) {
    int qrow = (qg*2 + qq)*64 + wid*16 + lr;
    aq[qq][0] = *(const s16x8*)&Qb[(size_t)qrow*64 + lg*8];
    aq[qq][1] = *(const s16x8*)&Qb[(size_t)qrow*64 + 32 + lg*8];
  }
  f32x4 oacc[2][4];
  f32x4 lacc[2];
  #pragma unroll
  for (int qq = 0; qq < 2; qq++) {
    lacc[qq] = (f32x4)0.f;
    #pragma unroll
    for (int ff = 0; ff < 4; ff++) oacc[qq][ff] = (f32x4)0.f;
  }
  u16* Pw = Ps + wid*16*72;
  uint4 pk[2], pv[2];
  #pragma unroll
  for (int p = 0; p < 2; p++) {
    int c = t + p*256; int r = c >> 3, cc = (c & 7)*8;
    pk[p] = *(const uint4*)&Kb[(size_t)r*64 + cc];
    pv[p] = *(const uint4*)&VTb[(size_t)r*4096 + cc];
  }
  for (int k0 = 0; k0 < 512; k0 += 64) {
    __syncthreads();
    #pragma unroll
    for (int p = 0; p < 2; p++) {
      int c = t + p*256; int r = c >> 3, cc = (c & 7)*8;
      *(uint4*)&Ks[r*72 + cc] = pk[p];
      *(uint4*)&Vs[r*72 + cc] = pv[p];
    }
    __syncthreads();
    if (k0 + 64 < 512) {
      #pragma unroll
      for (int p = 0; p < 2; p++) {
        int c = t + p*256; int r = c >> 3, cc = (c & 7)*8;
        pk[p] = *(const uint4*)&Kb[(size_t)(k0 + 64 + r)*64 + cc];
        pv[p] = *(const uint4*)&VTb[(size_t)r*4096 + k0 + 64 + cc];
      }
    }
    #pragma unroll
    for (int qq = 0; qq < 2; qq++) {
      f32x4 sf[4];
      #pragma unroll
      for (int ff = 0; ff < 4; ff++) {
        s16x8 b0 = *(s16x8*)&Ks[(ff*16 + lr)*72 + lg*8];
        s16x8 b1 = *(s16x8*)&Ks[(ff*16 + lr)*72 + 32 + lg*8];
        f32x4 s = (f32x4)0.f;
        s = MFMA16(aq[qq][0], b0, s);
        s = MFMA16(aq[qq][1], b1, s);
        sf[ff] = s;
      }
      #pragma unroll
      for (int r = 0; r < 4; r++) {
        #pragma unroll
        for (int ff = 0; ff < 4; ff++) {
          float pv2 = __expf(sf[ff][r] - 8.f);
          lacc[qq][r] += pv2;
          Pw[(lg*4 + r)*72 + ff*16 + lr] = f2b(pv2);
        }
      }
      #pragma unroll
      for (int ks = 0; ks < 2; ks++) {
        s16x8 ap = *(s16x8*)&Pw[lr*72 + ks*32 + lg*8];
        #pragma unroll
        for (int df = 0; df < 4; df++) {
          s16x8 bv = *(s16x8*)&Vs[(df*16 + lr)*72 + ks*32 + lg*8];
          oacc[qq][df] = MFMA16(ap, bv, oacc[qq][df]);
        }
      }
    }
  }
  #pragma unroll
  for (int qq = 0; qq < 2; qq++) {
    #pragma unroll
    for (int r = 0; r < 4; r++) {
      float s = lacc[qq][r];
      #pragma unroll
      for (int o = 1; o < 16; o <<= 1) s += __shfl_xor(s, o);
      lacc[qq][r] = s;
    }
  }
  #pragma unroll
  for (int qq = 0; qq < 2; qq++) {
    int pidx = (bh*4 + qg*2 + qq)*8 + ch;
    #pragma unroll
    for (int r = 0; r < 4; r++) {
      int lrow = wid*16 + lg*4 + r;
      if (lr == 0) pl[pidx*64 + lrow] = lacc[qq][r];
      uint2 pw2;
      pw2.x = (unsigned)f2b(oacc[qq][0][r]) | ((unsigned)f2b(oacc[qq][1][r]) << 16);
      pw2.y = (unsigned)f2b(oacc[qq][2][r]) | ((unsigned)f2b(oacc[qq][3][r]) << 16);
      *(uint2*)&po[((size_t)pidx*64 + lrow)*64 + lr*4] = pw2;
    }
  }
}

__device__ __forceinline__ void merge_body(int m, u16* tile,
    const u16* __restrict__ po, const float* __restrict__ pl, u16* __restrict__ a3vT) {
  int t = threadIdx.x;
  int qt = m & 3, bh = m >> 2;
  int lrow = t & 63, dg = t >> 6;
  int pbase = (bh*4 + qt)*8;
  float L = 0.f;
  #pragma unroll
  for (int ch = 0; ch < 8; ch++) L += pl[(pbase+ch)*64 + lrow];
  float Oacc[16];
  #pragma unroll
  for (int ss = 0; ss < 16; ss++) Oacc[ss] = 0.f;
  #pragma unroll
  for (int ch = 0; ch < 8; ch++) {
    const u16* pr = &po[(((size_t)(pbase+ch)*64 + lrow)*64) + dg*16];
    uint4 v0 = *(const uint4*)pr;
    uint4 v1 = *(const uint4*)(pr + 8);
    unsigned arr[8] = {v0.x, v0.y, v0.z, v0.w, v1.x, v1.y, v1.z, v1.w};
    #pragma unroll
    for (int jj = 0; jj < 8; jj++) {
      Oacc[jj*2]   += b2f((u16)(arr[jj] & 0xffff));
      Oacc[jj*2+1] += b2f((u16)(arr[jj] >> 16));
    }
  }
  float Linv = 1.f / L;
  #pragma unroll
  for (int ss = 0; ss < 16; ss++) {
    int s = dg*16 + ss;
    int c = ((s & 3) << 4) | (s >> 2);
    tile[c*72 + lrow] = f2b(Oacc[ss] * Linv);
  }
  __syncthreads();
  #pragma unroll
  for (int p = 0; p < 2; p++) {
    int idx = t + p*256;
    int d = idx >> 3, seg = idx & 7;
    u16 tmp[8];
    #pragma unroll
    for (int j = 0; j < 8; j++) tmp[j] = tile[d*72 + seg*8 + j];
    *(uint4*)&a3vT[((size_t)bh*64 + d)*256 + qt*64 + seg*8] = *(uint4*)tmp;
  }
}

// ---------------- pinv stage 1 (optionally fused with flash / merge; optional inv scale) ----------------
__global__ __launch_bounds__(256) void pinv_s1_f(int mode,
    const u16* __restrict__ a2h, const u16* __restrict__ zcT,
    u16* __restrict__ xz, u16* __restrict__ xzT, u16* __restrict__ e1T,
    const unsigned* __restrict__ scal,
    const u16* __restrict__ Q, const u16* __restrict__ Kg, const u16* __restrict__ VT,
    u16* __restrict__ po, float* __restrict__ pl, u16* __restrict__ a3vT) {
  __shared__ __align__(16) u16 smem[13824];
  int bI = blockIdx.x;
  if (bI < 512) {
    float sc = (mode == 1) ? 1.f/__uint_as_float(scal[1]) : 1.f;
    s1_body(bI, smem, smem + 4608, a2h, zcT, xz, xzT, e1T, sc);
  } else if (mode == 1) {
    flash_body(bI - 512, smem, Q, Kg, VT, po, pl);
  } else {
    merge_body(bI - 512, smem, po, pl, a3vT);
  }
}

// ---------------- pinv stage 2 (optional inv scale on W half) ----------------
__global__ __launch_bounds__(256) void pinv_s2(const u16* __restrict__ xz, const u16* __restrict__ e1T,
    const u16* __restrict__ zc, const u16* __restrict__ xzT,
    u16* __restrict__ e2T, u16* __restrict__ W,
    const unsigned* __restrict__ scal, int useInv) {
  __shared__ u16 As[64*72], Bs[64*72];
  int bz = blockIdx.z;
  bool isQ = bz < 32;
  size_t bb = (size_t)(isQ ? bz : bz - 32) << 16;
  const u16* Aptr = (isQ ? xz : zc) + bb;
  const u16* Bptr = (isQ ? e1T : xzT) + bb;
  f32x4 acc[2][2];
  #pragma unroll
  for (int i = 0; i < 2; i++) { acc[i][0] = (f32x4)0.f; acc[i][1] = (f32x4)0.f; }
  int row0 = blockIdx.y*64, col0 = blockIdx.x*64;
  gemm64_pf(Aptr, Bptr, row0, col0, As, Bs, acc);
  float scw = useInv ? 1.f/__uint_as_float(scal[1]) : 1.f;
  int t = threadIdx.x, lane = t & 63, wid = t >> 6, lr = lane & 15, lg = lane >> 4;
  int wr = (wid >> 1)*32, wc = (wid & 1)*32;
  #pragma unroll
  for (int i = 0; i < 2; i++)
    #pragma unroll
    for (int j = 0; j < 2; j++)
      #pragma unroll
      for (int r = 0; r < 4; r++) {
        int row = row0 + wr + i*16 + lg*4 + r;
        int col = col0 + wc + j*16 + lr;
        float c = acc[i][j][r];
        if (isQ) e2T[bb + (size_t)col*256 + row] = f2b((row == col ? 15.f : 0.f) - c);
        else     W  [bb + (size_t)row*256 + col] = f2b(c * scw);
      }
}

// ---------------- pinv stage 3 (optional inv scale on z term) ----------------
__global__ __launch_bounds__(256) void pinv_s3(const u16* __restrict__ W, const u16* __restrict__ e2T,
    const u16* __restrict__ zc, u16* __restrict__ zn, u16* __restrict__ znT,
    const unsigned* __restrict__ scal, int useInv) {
  __shared__ u16 As[64*72], Bs[64*72];
  size_t bb = (size_t)blockIdx.z << 16;
  f32x4 acc[2][2];
  #pragma unroll
  for (int i = 0; i < 2; i++) { acc[i][0] = (f32x4)0.f; acc[i][1] = (f32x4)0.f; }
  int row0 = blockIdx.y*64, col0 = blockIdx.x*64;
  gemm64_pf(W + bb, e2T + bb, row0, col0, As, Bs, acc);
  float zsc = useInv ? 3.25f/__uint_as_float(scal[1]) : 3.25f;
  int t = threadIdx.x, lane = t & 63, wid = t >> 6, lr = lane & 15, lg = lane >> 4;
  int wr = (wid >> 1)*32, wc = (wid & 1)*32;
  #pragma unroll
  for (int i = 0; i < 2; i++)
    #pragma unroll
    for (int j = 0; j < 2; j++)
      #pragma unroll
      for (int r = 0; r < 4; r++) {
        int row = row0 + wr + i*16 + lg*4 + r;
        int col = col0 + wc + j*16 + lr;
        size_t idx = bb + (size_t)row*256 + col;
        float val = zsc*b2f(zc[idx]) - 0.25f*acc[i][j][r];
        zn [idx] = f2b(val);
        znT[bb + (size_t)col*256 + row] = f2b(val);
      }
}

// ---------------- batched 64x64-tile MFMA GEMM (final w2T), BK=32 prefetch ----------------
__global__ __launch_bounds__(256) void bmm64(const u16* __restrict__ A, const u16* __restrict__ BT,
    u16* __restrict__ CT, int M, int N, int K) {
  __shared__ u16 As[64*40], Bs[64*40];
  int batch = blockIdx.z;
  const u16* Ab = A  + (size_t)batch*M*K;
  const u16* Bb = BT + (size_t)batch*N*K;
  int row0 = blockIdx.y*64, col0 = blockIdx.x*64;
  int t = threadIdx.x, lane = t & 63, wid = t >> 6, lr = lane & 15, lg = lane >> 4;
  int wr = (wid >> 1)*32, wc = (wid & 1)*32;
  int sr = t >> 2, sc = (t & 3)*8;
  const u16* Arow = Ab + (size_t)(row0 + sr)*K + sc;
  const u16* Brow = Bb + (size_t)(col0 + sr)*K + sc;
  uint4 pa = *(const uint4*)Arow;
  uint4 pb = *(const uint4*)Brow;
  f32x4 acc[2][2];
  #pragma unroll
  for (int i = 0; i < 2; i++)
    #pragma unroll
    for (int j = 0; j < 2; j++) acc[i][j] = (f32x4)0.f;
  for (int k0 = 0; k0 < K; k0 += 32) {
    __syncthreads();
    *(uint4*)&As[sr*40 + sc] = pa;
    *(uint4*)&Bs[sr*40 + sc] = pb;
    __syncthreads();
    if (k0 + 32 < K) {
      pa = *(const uint4*)(Arow + k0 + 32);
      pb = *(const uint4*)(Brow + k0 + 32);
    }
    s16x8 af[2], bf[2];
    #pragma unroll
    for (int f = 0; f < 2; f++) {
      af[f] = *(s16x8*)&As[(wr + f*16 + lr)*40 + lg*8];
      bf[f] = *(s16x8*)&Bs[(wc + f*16 + lr)*40 + lg*8];
    }
    #pragma unroll
    for (int i = 0; i < 2; i++)
      #pragma unroll
      for (int j = 0; j < 2; j++)
        acc[i][j] = MFMA16(af[i], bf[j], acc[i][j]);
  }
  size_t cb = (size_t)batch*M*N;
  #pragma unroll
  for (int i = 0; i < 2; i++)
    #pragma unroll
    for (int j = 0; j < 2; j++)
      #pragma unroll
      for (int r = 0; r < 4; r++) {
        int row = row0 + wr + i*16 + lg*4 + r;
        int col = col0 + wc + j*16 + lr;
        CT[cb + (size_t)col*M + row] = f2b(acc[i][j][r]);
      }
}

// ---------------- fixed-shift softmax flash: outh += softmax(q @ kl^T) @ w2 ----------------
__global__ __launch_bounds__(256, 4) void flash_a1(const u16* __restrict__ Q, const u16* __restrict__ Kl,
    const u16* __restrict__ W2T, u16* __restrict__ outh) {
  __shared__ u16 Ks[64*72];
  __shared__ u16 Vs[64*264];
  __shared__ u16 Ps[4*16*264];
  int bh = blockIdx.y;
  int q0 = blockIdx.x * 64;
  int t = threadIdx.x, lane = t & 63, wid = t >> 6, lr = lane & 15, lg = lane >> 4;
  const u16* Qb = Q + ((size_t)bh*4096)*64;
  #pragma unroll
  for (int p = 0; p < 8; p++) {
    int c = t + p*256; int r = c >> 5, col = (c & 31)*8;
    *(uint4*)&Vs[r*264 + col] = *(const uint4*)&W2T[((size_t)bh*64 + r)*256 + col];
  }
  int qrow = q0 + wid*16 + lr;
  s16x8 aq0 = *(const s16x8*)&Qb[(size_t)qrow*64 + lg*8];
  s16x8 aq1 = *(const s16x8*)&Qb[(size_t)qrow*64 + 32 + lg*8];
  f32x4 sf[16];
  #pragma unroll
  for (int f = 0; f < 16; f++) sf[f] = (f32x4)0.f;
  #pragma unroll
  for (int kt = 0; kt < 4; kt++) {
    __syncthreads();
    #pragma unroll
    for (int p = 0; p < 2; p++) {
      int c = t + p*256; int r = c >> 3, cc = (c & 7)*8;
      *(uint4*)&Ks[r*72 + cc] = *(const uint4*)&Kl[((size_t)bh*256 + kt*64 + r)*64 + cc];
    }
    __syncthreads();
    #pragma unroll
    for (int f2 = 0; f2 < 4; f2++) {
      s16x8 b0 = *(s16x8*)&Ks[(f2*16 + lr)*72 + lg*8];
      s16x8 b1 = *(s16x8*)&Ks[(f2*16 + lr)*72 + 32 + lg*8];
      sf[kt*4 + f2] = MFMA16(aq1, b1, MFMA16(aq0, b0, sf[kt*4 + f2]));
    }
  }
  u16* Pw = Ps + wid*16*264;
  float linv[4];
  #pragma unroll
  for (int r = 0; r < 4; r++) {
    float sum = 0.f;
    #pragma unroll
    for (int f = 0; f < 16; f++) {
      float pv = __expf(sf[f][r] - 8.f);
      sum += pv;
      Pw[(lg*4 + r)*264 + f*16 + lr] = f2b(pv);
    }
    #pragma unroll
    for (int o = 1; o < 16; o <<= 1) sum += __shfl_xor(sum, o);
    linv[r] = 1.f / sum;
  }
  f32x4 oacc[4];
  #pragma unroll
  for (int f = 0; f < 4; f++) oacc[f] = (f32x4)0.f;
  #pragma unroll
  for (int ks = 0; ks < 8; ks++) {
    s16x8 ap = *(s16x8*)&Pw[lr*264 + ks*32 + lg*8];
    #pragma unroll
    for (int df = 0; df < 4; df++) {
      s16x8 bv = *(s16x8*)&Vs[(df*16 + lr)*264 + ks*32 + lg*8];
      oacc[df] = MFMA16(ap, bv, oacc[df]);
    }
  }
  int b = bh >> 3, h = bh & 7;
  #pragma unroll
  for (int df = 0; df < 4; df++)
    #pragma unroll
    for (int r = 0; r < 4; r++) {
      int lrow = wid*16 + lg*4 + r;
      int col = df*16 + lr;
      size_t oi = ((size_t)(b*4096 + q0 + lrow))*512 + h*64 + col;
      outh[oi] = f2b(b2f(outh[oi]) + oacc[df][r] * linv[r]);
    }
}

extern "C" void kernel_launch(void* const* d_in, const int* in_sizes, int n_in,
                              void* d_out, int out_size, void* d_ws, size_t ws_size,
                              hipStream_t stream) {
  const float* x      = (const float*)d_in[0];
  const float* norm_w = (const float*)d_in[1];
  const float* norm_b = (const float*)d_in[2];
  const float* w_qkv  = (const float*)d_in[3];
  const float* w_out  = (const float*)d_in[4];
  const float* b_out  = (const float*)d_in[5];
  const float* res_w  = (const float*)d_in[6];
  float* out = (float*)d_out;
  char* ws = (char*)d_ws;

  size_t off = 0;
  u16* xn    = (u16*)(ws + off); off += 16777216;
  u16* q     = (u16*)(ws + off); off += 16777216;
  u16* k     = (u16*)(ws + off); off += 16777216;
  u16* v     = (u16*)(ws + off); off += 16777216;
  u16* vT    = (u16*)(ws + off); off += 16777216;
  u16* ql    = (u16*)(ws + off); off += 1048576;
  u16* kl    = (u16*)(ws + off); off += 1048576;
  u16* a2h   = (u16*)(ws + off); off += 4194304;
  u16* zA    = (u16*)(ws + off); off += 4194304;   // a2hT during it-1, then z iterate
  u16* zAT   = (u16*)(ws + off); off += 4194304;
  u16* zB    = (u16*)(ws + off); off += 4194304;
  u16* zBT   = (u16*)(ws + off); off += 4194304;
  u16* xz    = (u16*)(ws + off); off += 4194304;
  u16* xzT   = (u16*)(ws + off); off += 4194304;
  u16* e1T   = (u16*)(ws + off); off += 4194304;
  u16* e2T   = (u16*)(ws + off); off += 4194304;
  u16* Wm    = (u16*)(ws + off); off += 4194304;
  u16* a3vT  = (u16*)(ws + off); off += 1048576;
  u16* w2T   = (u16*)(ws + off); off += 1048576;
  u16* wqkvT = (u16*)(ws + off); off += 1572864;
  u16* woutT = (u16*)(ws + off); off += 524288;
  u16* outh  = (u16*)(ws + off); off += 16777216;
  u16* po    = (u16*)(ws + off); off += 8388608;
  float* pl  = (float*)(ws + off); off += 262144;
  float* pcs = (float*)(ws + off); off += 131072;
  unsigned* scal = (unsigned*)(ws + off); off += 8;

  prep_kernel<<<20480, 256, 0, stream>>>(x, norm_w, norm_b, xn, w_qkv, wqkvT, w_out, woutT, scal);
  qkv_mfma<<<1536, 256, 0, stream>>>(xn, wqkvT, q, k, v, ql, kl);
  mid_kernel<<<3200, 256, 0, stream>>>(v, vT, ql, kl, a2h, /*a2hT=*/zA, pcs, res_w, outh);
  colmax_kernel<<<32, 256, 0, stream>>>(pcs, scal);

  // iteration 1: inv folded into epilogues; flash fused into s1
  pinv_s1_f<<<1024, 256, 0, stream>>>(1, a2h, /*zcT=*/a2h, xz, xzT, e1T, scal, ql, k, vT, po, pl, a3vT);
  pinv_s2<<<dim3(4,4,64), 256, 0, stream>>>(xz, e1T, /*zc=*/zA, xzT, e2T, Wm, scal, 1);
  pinv_s3<<<dim3(4,4,32), 256, 0, stream>>>(Wm, e2T, /*zc=*/zA, zB, zBT, scal, 1);
  // iteration 2: merge fused into s1
  pinv_s1_f<<<640, 256, 0, stream>>>(2, a2h, zBT, xz, xzT, e1T, scal, ql, k, vT, po, pl, a3vT);
  pinv_s2<<<dim3(4,4,64), 256, 0, stream>>>(xz, e1T, zB, xzT, e2T, Wm, scal, 0);
  pinv_s3<<<dim3(4,4,32), 256, 0, stream>>>(Wm, e2T, zB, zA, zAT, scal, 0);
  // iterations 3-6
  u16 *zc = zA, *zcT = zAT, *zn = zB, *znT = zBT;
  for (int it = 0; it < 4; it++) {
    pinv_s1_f<<<512, 256, 0, stream>>>(0, a2h, zcT, xz, xzT, e1T, scal, ql, k, vT, po, pl, a3vT);
    pinv_s2<<<dim3(4,4,64), 256, 0, stream>>>(xz, e1T, zc, xzT, e2T, Wm, scal, 0);
    pinv_s3<<<dim3(4,4,32), 256, 0, stream>>>(Wm, e2T, zc, zn, znT, scal, 0);
    u16* tp;
    tp = zc; zc = zn; zn = tp;
    tp = zcT; zcT = znT; znT = tp;
  }
  // after 4 swaps starting at zA: final z is back in zA
  bmm64<<<dim3(1,4,32), 256, 0, stream>>>(zA, a3vT, w2T, 256, 64, 256);
  flash_a1<<<dim3(64, 32), 256, 0, stream>>>(q, kl, w2T, outh);
  out_mfma<<<512, 256, 0, stream>>>(outh, woutT, b_out, x, out);
}

// Round 21
// 382.643 us; speedup vs baseline: 1.0114x; 1.0114x over previous
//
#include <hip/hip_runtime.h>
#include <math.h>

typedef unsigned short u16;
typedef short s16x8 __attribute__((ext_vector_type(8)));
typedef float f32x4 __attribute__((ext_vector_type(4)));

#define MFMA16(a, b, c) __builtin_amdgcn_mfma_f32_16x16x32_bf16((a), (b), (c), 0, 0, 0)

__device__ __forceinline__ u16 f2b(float f) {
  unsigned u = __float_as_uint(f);
  unsigned r = (u + 0x7fff + ((u >> 16) & 1)) >> 16;
  return (u16)r;
}
__device__ __forceinline__ float b2f(u16 h) { return __uint_as_float(((unsigned)h) << 16); }

// ---------------- fused prep: LayerNorm + both weight transposes + scal init ----------------
__global__ __launch_bounds__(256) void prep_kernel(const float* __restrict__ x, const float* __restrict__ w,
    const float* __restrict__ b, u16* __restrict__ xn,
    const float* __restrict__ Wq, u16* __restrict__ WqT,
    const float* __restrict__ Wo, u16* __restrict__ WoT,
    unsigned* __restrict__ scal) {
  int bI = blockIdx.x;
  int t = threadIdx.x;
  if (bI == 0 && t == 0) { scal[0] = 0u; scal[1] = 0u; }
  if (bI < 16384) {
    int row = bI;
    const float* xr = x + (size_t)row * 512;
    float v0 = xr[t], v1 = xr[t + 256];
    float s = v0 + v1, ss = v0*v0 + v1*v1;
    for (int o = 32; o > 0; o >>= 1) { s += __shfl_down(s, o); ss += __shfl_down(ss, o); }
    __shared__ float ls[4], lss[4];
    int wid = t >> 6, lane = t & 63;
    if (lane == 0) { ls[wid] = s; lss[wid] = ss; }
    __syncthreads();
    float tot  = ls[0]+ls[1]+ls[2]+ls[3];
    float tot2 = lss[0]+lss[1]+lss[2]+lss[3];
    float mean = tot * (1.f/512);
    float var  = tot2 * (1.f/512) - mean*mean;
    float inv = rsqrtf(var + 1e-5f);
    u16* xo = xn + (size_t)row * 512;
    xo[t]     = f2b((v0-mean)*inv*w[t]     + b[t]);
    xo[t+256] = f2b((v1-mean)*inv*w[t+256] + b[t+256]);
  } else if (bI < 16384 + 3072) {
    int idx = (bI - 16384)*256 + t;
    int r = idx / 1536, c = idx - r*1536;
    WqT[(size_t)c*512 + r] = f2b(Wq[idx]);
  } else {
    int idx = (bI - 19456)*256 + t;
    int r = idx >> 9, c = idx & 511;
    WoT[(size_t)c*512 + r] = f2b(Wo[idx]);
  }
}

// ---------------- 128x128 MFMA GEMM core, BK=32 + 1-deep register prefetch (proven) ----------------
__device__ __forceinline__ void gemm128_pf(const u16* __restrict__ A, const u16* __restrict__ BT,
    int K, int ldA, int ldBT, int row0, int col0, u16* As, u16* Bs, f32x4 acc[4][4]) {
  int t = threadIdx.x, lane = t & 63, wid = t >> 6;
  int wr = (wid >> 1) * 64, wc = (wid & 1) * 64;
  int lr = lane & 15, lg = lane >> 4;
  int sr = t >> 2, sc = (t & 3) * 8;
  const u16* Ar0 = A  + (size_t)(row0 + sr)*ldA + sc;
  const u16* Ar1 = A  + (size_t)(row0 + sr + 64)*ldA + sc;
  const u16* Br0 = BT + (size_t)(col0 + sr)*ldBT + sc;
  const u16* Br1 = BT + (size_t)(col0 + sr + 64)*ldBT + sc;
  uint4 pa0 = *(const uint4*)Ar0, pa1 = *(const uint4*)Ar1;
  uint4 pb0 = *(const uint4*)Br0, pb1 = *(const uint4*)Br1;
  for (int k0 = 0; k0 < K; k0 += 32) {
    __syncthreads();
    *(uint4*)&As[sr*40 + sc]        = pa0;
    *(uint4*)&As[(sr + 64)*40 + sc] = pa1;
    *(uint4*)&Bs[sr*40 + sc]        = pb0;
    *(uint4*)&Bs[(sr + 64)*40 + sc] = pb1;
    __syncthreads();
    if (k0 + 32 < K) {
      pa0 = *(const uint4*)(Ar0 + k0 + 32);
      pa1 = *(const uint4*)(Ar1 + k0 + 32);
      pb0 = *(const uint4*)(Br0 + k0 + 32);
      pb1 = *(const uint4*)(Br1 + k0 + 32);
    }
    s16x8 af[4], bf[4];
    #pragma unroll
    for (int f = 0; f < 4; f++) {
      af[f] = *(s16x8*)&As[(wr + f*16 + lr)*40 + lg*8];
      bf[f] = *(s16x8*)&Bs[(wc + f*16 + lr)*40 + lg*8];
    }
    #pragma unroll
    for (int i = 0; i < 4; i++)
      #pragma unroll
      for (int j = 0; j < 4; j++)
        acc[i][j] = MFMA16(af[i], bf[j], acc[i][j]);
  }
}

// ---------------- 64x64 MFMA GEMM core (K=256), BK=64 + register prefetch (proven) ----------------
__device__ __forceinline__ void gemm64_pf(const u16* __restrict__ Ab, const u16* __restrict__ Bb,
    int row0, int col0, u16* As, u16* Bs, f32x4 acc[2][2]) {
  int t = threadIdx.x, lane = t & 63, wid = t >> 6;
  int wr = (wid >> 1)*32, wc = (wid & 1)*32;
  int lr = lane & 15, lg = lane >> 4;
  int sr = t >> 3, sc = (t & 7)*8;
  const u16* Ar0 = Ab + (size_t)(row0 + sr)*256 + sc;
  const u16* Ar1 = Ab + (size_t)(row0 + 32 + sr)*256 + sc;
  const u16* Br0 = Bb + (size_t)(col0 + sr)*256 + sc;
  const u16* Br1 = Bb + (size_t)(col0 + 32 + sr)*256 + sc;
  uint4 pa0 = *(const uint4*)Ar0, pa1 = *(const uint4*)Ar1;
  uint4 pb0 = *(const uint4*)Br0, pb1 = *(const uint4*)Br1;
  for (int k0 = 0; k0 < 256; k0 += 64) {
    __syncthreads();
    *(uint4*)&As[sr*72 + sc]        = pa0;
    *(uint4*)&As[(sr + 32)*72 + sc] = pa1;
    *(uint4*)&Bs[sr*72 + sc]        = pb0;
    *(uint4*)&Bs[(sr + 32)*72 + sc] = pb1;
    __syncthreads();
    if (k0 + 64 < 256) {
      pa0 = *(const uint4*)(Ar0 + k0 + 64);
      pa1 = *(const uint4*)(Ar1 + k0 + 64);
      pb0 = *(const uint4*)(Br0 + k0 + 64);
      pb1 = *(const uint4*)(Br1 + k0 + 64);
    }
    #pragma unroll
    for (int kk = 0; kk < 2; kk++) {
      s16x8 af[2], bf[2];
      #pragma unroll
      for (int f = 0; f < 2; f++) {
        af[f] = *(s16x8*)&As[(wr + f*16 + lr)*72 + kk*32 + lg*8];
        bf[f] = *(s16x8*)&Bs[(wc + f*16 + lr)*72 + kk*32 + lg*8];
      }
      #pragma unroll
      for (int i = 0; i < 2; i++)
        #pragma unroll
        for (int j = 0; j < 2; j++)
          acc[i][j] = MFMA16(af[i], bf[j], acc[i][j]);
    }
  }
}

// ---------------- QKV (XCD-swizzled) + fused landmarks ----------------
__global__ __launch_bounds__(256, 4) void qkv_mfma(const u16* __restrict__ xn, const u16* __restrict__ wT,
    u16* __restrict__ q, u16* __restrict__ k, u16* __restrict__ v,
    u16* __restrict__ ql, u16* __restrict__ kl) {
  __shared__ u16 As[128*40], Bs[128*40];
  f32x4 acc[4][4];
  #pragma unroll
  for (int i = 0; i < 4; i++)
    #pragma unroll
    for (int j = 0; j < 4; j++) acc[i][j] = (f32x4)0.f;
  int bI = blockIdx.x;
  int job = (bI & 7)*192 + (bI >> 3);
  int row0 = (job / 12) * 128, col0 = (job % 12) * 128;
  gemm128_pf(xn, wT, 512, 512, 512, row0, col0, As, Bs, acc);
  int t = threadIdx.x, lane = t & 63, wid = t >> 6, lr = lane & 15, lg = lane >> 4;
  int wr = (wid >> 1)*64, wc = (wid & 1)*64;
  int part = col0 >> 9;
  #pragma unroll
  for (int i = 0; i < 4; i++)
    #pragma unroll
    for (int j = 0; j < 4; j++)
      #pragma unroll
      for (int r = 0; r < 4; r++) {
        int row = row0 + wr + i*16 + lg*4 + r;
        int col = col0 + wc + j*16 + lr;
        float val = acc[i][j][r];
        int rem = col & 511, h = rem >> 6, d = rem & 63;
        int b = row >> 12, n = row & 4095;
        size_t bh = (size_t)(b*8 + h);
        size_t dst = (bh*4096 + n)*64 + d;
        if (part == 0)      q[dst] = f2b(val * 0.125f);
        else if (part == 1) k[dst] = f2b(val);
        else                v[dst] = f2b(val);
      }
  if (part <= 1) {
    #pragma unroll
    for (int i = 0; i < 4; i++) {
      #pragma unroll
      for (int j = 0; j < 4; j++) {
        float s = acc[i][j][0] + acc[i][j][1] + acc[i][j][2] + acc[i][j][3];
        s += __shfl_xor(s, 16);
        s += __shfl_xor(s, 32);
        if (lg == 0) {
          int row16 = row0 + wr + i*16;
          int b = row16 >> 12, n = row16 & 4095;
          int m = n >> 4;
          int col = col0 + wc + j*16 + lr;
          int rem = col & 511, h = rem >> 6, d = rem & 63;
          size_t dst = ((size_t)(b*8 + h)*256 + m)*64 + d;
          if (part == 0) ql[dst] = f2b(s * (0.125f/16.f));
          else           kl[dst] = f2b(s * (1.f/16.f));
        }
      }
    }
  }
}

// ---------------- out GEMM (XCD-swizzled) ----------------
__global__ __launch_bounds__(256, 4) void out_mfma(const u16* __restrict__ outh, const u16* __restrict__ wT,
    const float* __restrict__ bo, const float* __restrict__ x, float* __restrict__ out) {
  __shared__ u16 As[128*40], Bs[128*40];
  f32x4 acc[4][4];
  #pragma unroll
  for (int i = 0; i < 4; i++)
    #pragma unroll
    for (int j = 0; j < 4; j++) acc[i][j] = (f32x4)0.f;
  int bI = blockIdx.x;
  int job = (bI & 7)*64 + (bI >> 3);
  int row0 = (job / 4) * 128, col0 = (job % 4) * 128;
  gemm128_pf(outh, wT, 512, 512, 512, row0, col0, As, Bs, acc);
  int t = threadIdx.x, lane = t & 63, wid = t >> 6, lr = lane & 15, lg = lane >> 4;
  int wr = (wid >> 1)*64, wc = (wid & 1)*64;
  #pragma unroll
  for (int i = 0; i < 4; i++)
    #pragma unroll
    for (int j = 0; j < 4; j++)
      #pragma unroll
      for (int r = 0; r < 4; r++) {
        int row = row0 + wr + i*16 + lg*4 + r;
        int col = col0 + wc + j*16 + lr;
        size_t idx = (size_t)row*512 + col;
        out[idx] = x[idx] + acc[i][j][r] + bo[col];
      }
}

// ---------------- fused mid: sim2 (128) + vtrans (2048) + conv->outh (1024) ----------------
__global__ __launch_bounds__(256) void mid_kernel(
    const u16* __restrict__ v, u16* __restrict__ vT,
    const u16* __restrict__ ql, const u16* __restrict__ kl,
    u16* __restrict__ a2h, float* __restrict__ pcs,
    const float* __restrict__ rw, u16* __restrict__ outh) {
  __shared__ __align__(16) u16 smem[25600];
  int bI = blockIdx.x;
  int t = threadIdx.x;
  if (bI < 128) {
    int rq = bI & 3, bh = bI >> 2;
    u16* Qs  = smem;
    u16* Ks2 = smem + 4608;
    float* wcol = (float*)(smem + 23040);
    int lane = t & 63, wid = t >> 6, lr = lane & 15, lg = lane >> 4;
    #pragma unroll
    for (int p = 0; p < 2; p++) {
      int c = t + p*256;
      int r = c >> 3, col = (c & 7)*8;
      *(uint4*)&Qs[r*72 + col] = *(const uint4*)&ql[((size_t)bh*256 + rq*64 + r)*64 + col];
    }
    #pragma unroll
    for (int p = 0; p < 8; p++) {
      int c = t + p*256;
      int r = c >> 3, col = (c & 7)*8;
      *(uint4*)&Ks2[r*72 + col] = *(const uint4*)&kl[((size_t)bh*256 + r)*64 + col];
    }
    __syncthreads();
    float colp[16];
    #pragma unroll
    for (int cf = 0; cf < 16; cf++) colp[cf] = 0.f;
    int rbase = wid*16;
    s16x8 a0 = *(s16x8*)&Qs[(rbase + lr)*72 + lg*8];
    s16x8 a1 = *(s16x8*)&Qs[(rbase + lr)*72 + 32 + lg*8];
    f32x4 sf[16];
    #pragma unroll
    for (int cf = 0; cf < 16; cf++) {
      s16x8 b0 = *(s16x8*)&Ks2[(cf*16 + lr)*72 + lg*8];
      s16x8 b1 = *(s16x8*)&Ks2[(cf*16 + lr)*72 + 32 + lg*8];
      sf[cf] = MFMA16(a1, b1, MFMA16(a0, b0, (f32x4)0.f));
    }
    #pragma unroll
    for (int r = 0; r < 4; r++) {
      float mx = -3e38f;
      #pragma unroll
      for (int cf = 0; cf < 16; cf++) mx = fmaxf(mx, sf[cf][r]);
      #pragma unroll
      for (int o = 1; o < 16; o <<= 1) mx = fmaxf(mx, __shfl_xor(mx, o));
      float sum = 0.f;
      #pragma unroll
      for (int cf = 0; cf < 16; cf++) { sf[cf][r] = __expf(sf[cf][r] - mx); sum += sf[cf][r]; }
      #pragma unroll
      for (int o = 1; o < 16; o <<= 1) sum += __shfl_xor(sum, o);
      float inv = 1.f / sum;
      int row = rq*64 + rbase + lg*4 + r;
      size_t base = (size_t)bh*65536 + (size_t)row*256;
      #pragma unroll
      for (int cf = 0; cf < 16; cf++) {
        float pp = sf[cf][r] * inv;
        a2h[base + cf*16 + lr] = f2b(pp);
        colp[cf] += pp;
      }
    }
    #pragma unroll
    for (int cf = 0; cf < 16; cf++) {
      colp[cf] += __shfl_xor(colp[cf], 16);
      colp[cf] += __shfl_xor(colp[cf], 32);
    }
    if (lg == 0) {
      #pragma unroll
      for (int cf = 0; cf < 16; cf++) wcol[wid*256 + cf*16 + lr] = colp[cf];
    }
    __syncthreads();
    pcs[((size_t)bh*4 + rq)*256 + t] = wcol[t] + wcol[256 + t] + wcol[512 + t] + wcol[768 + t];
  } else if (bI < 2176) {
    int idx = bI - 128;
    int bh = idx >> 6, n0 = (idx & 63) * 64;
    u16* tile = smem;
    const u16* vb = v + ((size_t)bh*4096 + n0)*64;
    #pragma unroll
    for (int p = 0; p < 2; p++) {
      int c = t + p*256;
      int r = c >> 3, col = (c & 7)*8;
      *(uint4*)&tile[r*72 + col] = *(const uint4*)&vb[(size_t)r*64 + col];
    }
    __syncthreads();
    #pragma unroll
    for (int p = 0; p < 2; p++) {
      int c = t + p*256;
      int d = c >> 3, ncol = (c & 7)*8;
      u16 tmp[8];
      #pragma unroll
      for (int j = 0; j < 8; j++) tmp[j] = tile[(ncol + j)*72 + d];
      *(uint4*)&vT[((size_t)bh*64 + d)*4096 + n0 + ncol] = *(uint4*)tmp;
    }
  } else {
    int idx = bI - 2176;
    int bh = idx >> 5, n0 = (idx & 31) * 128;
    int b = bh >> 3, h = bh & 7;
    u16* tile = smem;
    float* wsm = (float*)(smem + 11520);
    if (t < 33) wsm[t] = rw[h*33 + t];
    const u16* vb = v + ((size_t)bh*4096)*64;
    #pragma unroll
    for (int p = 0; p < 5; p++) {
      int c = t + p*256;
      int r = c >> 3, col = (c & 7)*8;
      int nn = n0 - 16 + r;
      uint4 val = make_uint4(0u,0u,0u,0u);
      if (nn >= 0 && nn < 4096) val = *(const uint4*)&vb[(size_t)nn*64 + col];
      *(uint4*)&tile[r*72 + col] = val;
    }
    __syncthreads();
    int d8 = (t & 7) * 8;
    int r0 = t >> 3;
    #pragma unroll
    for (int pass = 0; pass < 4; pass++) {
      int lrow = pass*32 + r0;
      float acc[8] = {};
      #pragma unroll
      for (int j = 0; j < 33; j++) {
        uint4 vv = *(uint4*)&tile[(lrow + j)*72 + d8];
        float w = wsm[j];
        acc[0] += b2f((u16)(vv.x & 0xffff)) * w;
        acc[1] += b2f((u16)(vv.x >> 16))    * w;
        acc[2] += b2f((u16)(vv.y & 0xffff)) * w;
        acc[3] += b2f((u16)(vv.y >> 16))    * w;
        acc[4] += b2f((u16)(vv.z & 0xffff)) * w;
        acc[5] += b2f((u16)(vv.z >> 16))    * w;
        acc[6] += b2f((u16)(vv.w & 0xffff)) * w;
        acc[7] += b2f((u16)(vv.w >> 16))    * w;
      }
      size_t oi = ((size_t)(b*4096 + n0 + lrow))*512 + h*64 + d8;
      uint4 nv;
      nv.x = (unsigned)f2b(acc[0]) | ((unsigned)f2b(acc[1]) << 16);
      nv.y = (unsigned)f2b(acc[2]) | ((unsigned)f2b(acc[3]) << 16);
      nv.z = (unsigned)f2b(acc[4]) | ((unsigned)f2b(acc[5]) << 16);
      nv.w = (unsigned)f2b(acc[6]) | ((unsigned)f2b(acc[7]) << 16);
      *(uint4*)&outh[oi] = nv;
    }
  }
}

// ---------------- fused flash_part (512) + colmax (32) ----------------
__global__ __launch_bounds__(256) void fp_cm(const u16* __restrict__ Q, const u16* __restrict__ Kg,
    const u16* __restrict__ VT, u16* __restrict__ po, float* __restrict__ pl,
    const float* __restrict__ pcs, unsigned* __restrict__ scal) {
  __shared__ __align__(16) u16 smem[13824];
  int bI = blockIdx.x;
  int t = threadIdx.x;
  if (bI >= 512) {
    float* red = (float*)smem;
    int bh = bI - 512;
    size_t b4 = (size_t)bh*4*256;
    red[t] = pcs[b4 + t] + pcs[b4 + 256 + t] + pcs[b4 + 512 + t] + pcs[b4 + 768 + t];
    __syncthreads();
    for (int o = 128; o > 0; o >>= 1) {
      if (t < o) red[t] = fmaxf(red[t], red[t+o]);
      __syncthreads();
    }
    if (t == 0) atomicMax(scal + 1, __float_as_uint(red[0]));
    return;
  }
  int ch = bI & 7, qg = (bI >> 3) & 1, bh = bI >> 4;
  u16* Ks = smem;
  u16* Vs = smem + 4608;
  u16* Ps = smem + 9216;
  int lane = t & 63, wid = t >> 6, lr = lane & 15, lg = lane >> 4;
  const u16* Qb  = Q  + ((size_t)bh*256)*64;
  const u16* Kb  = Kg + ((size_t)bh*4096 + ch*512)*64;
  const u16* VTb = VT + ((size_t)bh*64)*4096 + ch*512;
  s16x8 aq[2][2];
  #pragma unroll
  for (int qq = 0; qq < 2; qq++) {
    int qrow = (qg*2 + qq)*64 + wid*16 + lr;
    aq[qq][0] = *(const s16x8*)&Qb[(size_t)qrow*64 + lg*8];
    aq[qq][1] = *(const s16x8*)&Qb[(size_t)qrow*64 + 32 + lg*8];
  }
  f32x4 oacc[2][4];
  f32x4 lacc[2];
  #pragma unroll
  for (int qq = 0; qq < 2; qq++) {
    lacc[qq] = (f32x4)0.f;
    #pragma unroll
    for (int f = 0; f < 4; f++) oacc[qq][f] = (f32x4)0.f;
  }
  u16* Pw = Ps + wid*16*72;
  uint4 pk[2], pv[2];
  #pragma unroll
  for (int p = 0; p < 2; p++) {
    int c = t + p*256; int r = c >> 3, cc = (c & 7)*8;
    pk[p] = *(const uint4*)&Kb[(size_t)r*64 + cc];
    pv[p] = *(const uint4*)&VTb[(size_t)r*4096 + cc];
  }
  for (int k0 = 0; k0 < 512; k0 += 64) {
    __syncthreads();
    #pragma unroll
    for (int p = 0; p < 2; p++) {
      int c = t + p*256; int r = c >> 3, cc = (c & 7)*8;
      *(uint4*)&Ks[r*72 + cc] = pk[p];
      *(uint4*)&Vs[r*72 + cc] = pv[p];
    }
    __syncthreads();
    if (k0 + 64 < 512) {
      #pragma unroll
      for (int p = 0; p < 2; p++) {
        int c = t + p*256; int r = c >> 3, cc = (c & 7)*8;
        pk[p] = *(const uint4*)&Kb[(size_t)(k0 + 64 + r)*64 + cc];
        pv[p] = *(const uint4*)&VTb[(size_t)r*4096 + k0 + 64 + cc];
      }
    }
    #pragma unroll
    for (int qq = 0; qq < 2; qq++) {
      f32x4 sf[4];
      #pragma unroll
      for (int f = 0; f < 4; f++) {
        s16x8 b0 = *(s16x8*)&Ks[(f*16 + lr)*72 + lg*8];
        s16x8 b1 = *(s16x8*)&Ks[(f*16 + lr)*72 + 32 + lg*8];
        f32x4 s = (f32x4)0.f;
        s = MFMA16(aq[qq][0], b0, s);
        s = MFMA16(aq[qq][1], b1, s);
        sf[f] = s;
      }
      #pragma unroll
      for (int r = 0; r < 4; r++) {
        #pragma unroll
        for (int f = 0; f < 4; f++) {
          float pv2 = __expf(sf[f][r] - 8.f);
          lacc[qq][r] += pv2;
          Pw[(lg*4 + r)*72 + f*16 + lr] = f2b(pv2);
        }
      }
      #pragma unroll
      for (int ks = 0; ks < 2; ks++) {
        s16x8 ap = *(s16x8*)&Pw[lr*72 + ks*32 + lg*8];
        #pragma unroll
        for (int df = 0; df < 4; df++) {
          s16x8 bv = *(s16x8*)&Vs[(df*16 + lr)*72 + ks*32 + lg*8];
          oacc[qq][df] = MFMA16(ap, bv, oacc[qq][df]);
        }
      }
    }
  }
  #pragma unroll
  for (int qq = 0; qq < 2; qq++) {
    #pragma unroll
    for (int r = 0; r < 4; r++) {
      float s = lacc[qq][r];
      #pragma unroll
      for (int o = 1; o < 16; o <<= 1) s += __shfl_xor(s, o);
      lacc[qq][r] = s;
    }
  }
  #pragma unroll
  for (int qq = 0; qq < 2; qq++) {
    int pidx = (bh*4 + qg*2 + qq)*8 + ch;
    #pragma unroll
    for (int r = 0; r < 4; r++) {
      int lrow = wid*16 + lg*4 + r;
      if (lr == 0) pl[pidx*64 + lrow] = lacc[qq][r];
      uint2 pw2;
      pw2.x = (unsigned)f2b(oacc[qq][0][r]) | ((unsigned)f2b(oacc[qq][1][r]) << 16);
      pw2.y = (unsigned)f2b(oacc[qq][2][r]) | ((unsigned)f2b(oacc[qq][3][r]) << 16);
      *(uint2*)&po[((size_t)pidx*64 + lrow)*64 + lr*4] = pw2;
    }
  }
}

// ---------------- fused merge(8 partials, unweighted) + z0 (bf16 source) ----------------
__global__ __launch_bounds__(256) void merge_z0(const u16* __restrict__ po,
    const float* __restrict__ pl, u16* __restrict__ a3vT,
    const u16* __restrict__ a2h, const unsigned* __restrict__ scal,
    u16* __restrict__ zA, u16* __restrict__ zAT) {
  __shared__ u16 tile[64*72];
  int bI = blockIdx.x;
  int t = threadIdx.x;
  if (bI < 128) {
    int qt = bI & 3, bh = bI >> 2;
    int lrow = t & 63, dg = t >> 6;
    int pbase = (bh*4 + qt)*8;
    float L = 0.f;
    #pragma unroll
    for (int ch = 0; ch < 8; ch++) L += pl[(pbase+ch)*64 + lrow];
    float Oacc[16];
    #pragma unroll
    for (int ss = 0; ss < 16; ss++) Oacc[ss] = 0.f;
    #pragma unroll
    for (int ch = 0; ch < 8; ch++) {
      const u16* pr = &po[(((size_t)(pbase+ch)*64 + lrow)*64) + dg*16];
      uint4 v0 = *(const uint4*)pr;
      uint4 v1 = *(const uint4*)(pr + 8);
      unsigned arr[8] = {v0.x, v0.y, v0.z, v0.w, v1.x, v1.y, v1.z, v1.w};
      #pragma unroll
      for (int jj = 0; jj < 8; jj++) {
        Oacc[jj*2]   += b2f((u16)(arr[jj] & 0xffff));
        Oacc[jj*2+1] += b2f((u16)(arr[jj] >> 16));
      }
    }
    float Linv = 1.f / L;
    #pragma unroll
    for (int ss = 0; ss < 16; ss++) {
      int s = dg*16 + ss;
      int c = ((s & 3) << 4) | (s >> 2);
      tile[c*72 + lrow] = f2b(Oacc[ss] * Linv);
    }
    __syncthreads();
    #pragma unroll
    for (int p = 0; p < 2; p++) {
      int idx = t + p*256;
      int d = idx >> 3, seg = idx & 7;
      u16 tmp[8];
      #pragma unroll
      for (int j = 0; j < 8; j++) tmp[j] = tile[d*72 + seg*8 + j];
      *(uint4*)&a3vT[((size_t)bh*64 + d)*256 + qt*64 + seg*8] = *(uint4*)tmp;
    }
  } else {
    size_t idx = (size_t)(bI - 128)*256 + t;
    float inv = 1.f / __uint_as_float(scal[1]);
    size_t bh = idx >> 16; int rem = (int)(idx & 65535); int i = rem >> 8, j = rem & 255;
    zA[idx]  = f2b(b2f(a2h[(bh<<16) + ((size_t)j<<8) + i]) * inv);
    zAT[idx] = f2b(b2f(a2h[idx]) * inv);
  }
}

// ---------------- pinv stage 1 ----------------
__global__ __launch_bounds__(256) void pinv_s1(const u16* __restrict__ a2h, const u16* __restrict__ zcT,
    u16* __restrict__ xz, u16* __restrict__ xzT, u16* __restrict__ e1T) {
  __shared__ u16 As[64*72], Bs[64*72];
  size_t bb = (size_t)blockIdx.z << 16;
  f32x4 acc[2][2];
  #pragma unroll
  for (int i = 0; i < 2; i++) { acc[i][0] = (f32x4)0.f; acc[i][1] = (f32x4)0.f; }
  int row0 = blockIdx.y*64, col0 = blockIdx.x*64;
  gemm64_pf(a2h + bb, zcT + bb, row0, col0, As, Bs, acc);
  int t = threadIdx.x, lane = t & 63, wid = t >> 6, lr = lane & 15, lg = lane >> 4;
  int wr = (wid >> 1)*32, wc = (wid & 1)*32;
  #pragma unroll
  for (int i = 0; i < 2; i++)
    #pragma unroll
    for (int j = 0; j < 2; j++)
      #pragma unroll
      for (int r = 0; r < 4; r++) {
        int row = row0 + wr + i*16 + lg*4 + r;
        int col = col0 + wc + j*16 + lr;
        float c = acc[i][j][r];
        xz [bb + (size_t)row*256 + col] = f2b(c);
        xzT[bb + (size_t)col*256 + row] = f2b(c);
        e1T[bb + (size_t)col*256 + row] = f2b((row == col ? 7.f : 0.f) - c);
      }
}

// ---------------- pinv stage 2 ----------------
__global__ __launch_bounds__(256) void pinv_s2(const u16* __restrict__ xz, const u16* __restrict__ e1T,
    const u16* __restrict__ zc, const u16* __restrict__ xzT,
    u16* __restrict__ e2T, u16* __restrict__ W) {
  __shared__ u16 As[64*72], Bs[64*72];
  int bz = blockIdx.z;
  bool isQ = bz < 32;
  size_t bb = (size_t)(isQ ? bz : bz - 32) << 16;
  const u16* Aptr = (isQ ? xz : zc) + bb;
  const u16* Bptr = (isQ ? e1T : xzT) + bb;
  f32x4 acc[2][2];
  #pragma unroll
  for (int i = 0; i < 2; i++) { acc[i][0] = (f32x4)0.f; acc[i][1] = (f32x4)0.f; }
  int row0 = blockIdx.y*64, col0 = blockIdx.x*64;
  gemm64_pf(Aptr, Bptr, row0, col0, As, Bs, acc);
  int t = threadIdx.x, lane = t & 63, wid = t >> 6, lr = lane & 15, lg = lane >> 4;
  int wr = (wid >> 1)*32, wc = (wid & 1)*32;
  #pragma unroll
  for (int i = 0; i < 2; i++)
    #pragma unroll
    for (int j = 0; j < 2; j++)
      #pragma unroll
      for (int r = 0; r < 4; r++) {
        int row = row0 + wr + i*16 + lg*4 + r;
        int col = col0 + wc + j*16 + lr;
        float c = acc[i][j][r];
        if (isQ) e2T[bb + (size_t)col*256 + row] = f2b((row == col ? 15.f : 0.f) - c);
        else     W  [bb + (size_t)row*256 + col] = f2b(c);
      }
}

// ---------------- pinv stage 3 ----------------
__global__ __launch_bounds__(256) void pinv_s3(const u16* __restrict__ W, const u16* __restrict__ e2T,
    const u16* __restrict__ zc, u16* __restrict__ zn, u16* __restrict__ znT) {
  __shared__ u16 As[64*72], Bs[64*72];
  size_t bb = (size_t)blockIdx.z << 16;
  f32x4 acc[2][2];
  #pragma unroll
  for (int i = 0; i < 2; i++) { acc[i][0] = (f32x4)0.f; acc[i][1] = (f32x4)0.f; }
  int row0 = blockIdx.y*64, col0 = blockIdx.x*64;
  gemm64_pf(W + bb, e2T + bb, row0, col0, As, Bs, acc);
  int t = threadIdx.x, lane = t & 63, wid = t >> 6, lr = lane & 15, lg = lane >> 4;
  int wr = (wid >> 1)*32, wc = (wid & 1)*32;
  #pragma unroll
  for (int i = 0; i < 2; i++)
    #pragma unroll
    for (int j = 0; j < 2; j++)
      #pragma unroll
      for (int r = 0; r < 4; r++) {
        int row = row0 + wr + i*16 + lg*4 + r;
        int col = col0 + wc + j*16 + lr;
        size_t idx = bb + (size_t)row*256 + col;
        float val = 3.25f*b2f(zc[idx]) - 0.25f*acc[i][j][r];
        zn [idx] = f2b(val);
        znT[bb + (size_t)col*256 + row] = f2b(val);
      }
}

// ---------------- batched 64x64-tile MFMA GEMM (final w2T), BK=32 prefetch ----------------
__global__ __launch_bounds__(256) void bmm64(const u16* __restrict__ A, const u16* __restrict__ BT,
    u16* __restrict__ CT, int M, int N, int K) {
  __shared__ u16 As[64*40], Bs[64*40];
  int batch = blockIdx.z;
  const u16* Ab = A  + (size_t)batch*M*K;
  const u16* Bb = BT + (size_t)batch*N*K;
  int row0 = blockIdx.y*64, col0 = blockIdx.x*64;
  int t = threadIdx.x, lane = t & 63, wid = t >> 6, lr = lane & 15, lg = lane >> 4;
  int wr = (wid >> 1)*32, wc = (wid & 1)*32;
  int sr = t >> 2, sc = (t & 3)*8;
  const u16* Arow = Ab + (size_t)(row0 + sr)*K + sc;
  const u16* Brow = Bb + (size_t)(col0 + sr)*K + sc;
  uint4 pa = *(const uint4*)Arow;
  uint4 pb = *(const uint4*)Brow;
  f32x4 acc[2][2];
  #pragma unroll
  for (int i = 0; i < 2; i++)
    #pragma unroll
    for (int j = 0; j < 2; j++) acc[i][j] = (f32x4)0.f;
  for (int k0 = 0; k0 < K; k0 += 32) {
    __syncthreads();
    *(uint4*)&As[sr*40 + sc] = pa;
    *(uint4*)&Bs[sr*40 + sc] = pb;
    __syncthreads();
    if (k0 + 32 < K) {
      pa = *(const uint4*)(Arow + k0 + 32);
      pb = *(const uint4*)(Brow + k0 + 32);
    }
    s16x8 af[2], bf[2];
    #pragma unroll
    for (int f = 0; f < 2; f++) {
      af[f] = *(s16x8*)&As[(wr + f*16 + lr)*40 + lg*8];
      bf[f] = *(s16x8*)&Bs[(wc + f*16 + lr)*40 + lg*8];
    }
    #pragma unroll
    for (int i = 0; i < 2; i++)
      #pragma unroll
      for (int j = 0; j < 2; j++)
        acc[i][j] = MFMA16(af[i], bf[j], acc[i][j]);
  }
  size_t cb = (size_t)batch*M*N;
  #pragma unroll
  for (int i = 0; i < 2; i++)
    #pragma unroll
    for (int j = 0; j < 2; j++)
      #pragma unroll
      for (int r = 0; r < 4; r++) {
        int row = row0 + wr + i*16 + lg*4 + r;
        int col = col0 + wc + j*16 + lr;
        CT[cb + (size_t)col*M + row] = f2b(acc[i][j][r]);
      }
}

// ---------------- fixed-shift softmax flash: outh += softmax(q @ kl^T) @ w2 ----------------
__global__ __launch_bounds__(256, 4) void flash_a1(const u16* __restrict__ Q, const u16* __restrict__ Kl,
    const u16* __restrict__ W2T, u16* __restrict__ outh) {
  __shared__ u16 Ks[64*72];
  __shared__ u16 Vs[64*264];
  __shared__ u16 Ps[4*16*264];
  int bh = blockIdx.y;
  int q0 = blockIdx.x * 64;
  int t = threadIdx.x, lane = t & 63, wid = t >> 6, lr = lane & 15, lg = lane >> 4;
  const u16* Qb = Q + ((size_t)bh*4096)*64;
  #pragma unroll
  for (int p = 0; p < 8; p++) {
    int c = t + p*256; int r = c >> 5, col = (c & 31)*8;
    *(uint4*)&Vs[r*264 + col] = *(const uint4*)&W2T[((size_t)bh*64 + r)*256 + col];
  }
  int qrow = q0 + wid*16 + lr;
  s16x8 aq0 = *(const s16x8*)&Qb[(size_t)qrow*64 + lg*8];
  s16x8 aq1 = *(const s16x8*)&Qb[(size_t)qrow*64 + 32 + lg*8];
  f32x4 sf[16];
  #pragma unroll
  for (int f = 0; f < 16; f++) sf[f] = (f32x4)0.f;
  #pragma unroll
  for (int kt = 0; kt < 4; kt++) {
    __syncthreads();
    #pragma unroll
    for (int p = 0; p < 2; p++) {
      int c = t + p*256; int r = c >> 3, cc = (c & 7)*8;
      *(uint4*)&Ks[r*72 + cc] = *(const uint4*)&Kl[((size_t)bh*256 + kt*64 + r)*64 + cc];
    }
    __syncthreads();
    #pragma unroll
    for (int f2 = 0; f2 < 4; f2++) {
      s16x8 b0 = *(s16x8*)&Ks[(f2*16 + lr)*72 + lg*8];
      s16x8 b1 = *(s16x8*)&Ks[(f2*16 + lr)*72 + 32 + lg*8];
      sf[kt*4 + f2] = MFMA16(aq1, b1, MFMA16(aq0, b0, sf[kt*4 + f2]));
    }
  }
  u16* Pw = Ps + wid*16*264;
  float linv[4];
  #pragma unroll
  for (int r = 0; r < 4; r++) {
    float sum = 0.f;
    #pragma unroll
    for (int f = 0; f < 16; f++) {
      float pv = __expf(sf[f][r] - 8.f);
      sum += pv;
      Pw[(lg*4 + r)*264 + f*16 + lr] = f2b(pv);
    }
    #pragma unroll
    for (int o = 1; o < 16; o <<= 1) sum += __shfl_xor(sum, o);
    linv[r] = 1.f / sum;
  }
  f32x4 oacc[4];
  #pragma unroll
  for (int f = 0; f < 4; f++) oacc[f] = (f32x4)0.f;
  #pragma unroll
  for (int ks = 0; ks < 8; ks++) {
    s16x8 ap = *(s16x8*)&Pw[lr*264 + ks*32 + lg*8];
    #pragma unroll
    for (int df = 0; df < 4; df++) {
      s16x8 bv = *(s16x8*)&Vs[(df*16 + lr)*264 + ks*32 + lg*8];
      oacc[df] = MFMA16(ap, bv, oacc[df]);
    }
  }
  int b = bh >> 3, h = bh & 7;
  #pragma unroll
  for (int df = 0; df < 4; df++)
    #pragma unroll
    for (int r = 0; r < 4; r++) {
      int lrow = wid*16 + lg*4 + r;
      int col = df*16 + lr;
      size_t oi = ((size_t)(b*4096 + q0 + lrow))*512 + h*64 + col;
      outh[oi] = f2b(b2f(outh[oi]) + oacc[df][r] * linv[r]);
    }
}

extern "C" void kernel_launch(void* const* d_in, const int* in_sizes, int n_in,
                              void* d_out, int out_size, void* d_ws, size_t ws_size,
                              hipStream_t stream) {
  const float* x      = (const float*)d_in[0];
  const float* norm_w = (const float*)d_in[1];
  const float* norm_b = (const float*)d_in[2];
  const float* w_qkv  = (const float*)d_in[3];
  const float* w_out  = (const float*)d_in[4];
  const float* b_out  = (const float*)d_in[5];
  const float* res_w  = (const float*)d_in[6];
  float* out = (float*)d_out;
  char* ws = (char*)d_ws;

  size_t off = 0;
  u16* xn    = (u16*)(ws + off); off += 16777216;
  u16* q     = (u16*)(ws + off); off += 16777216;
  u16* k     = (u16*)(ws + off); off += 16777216;
  u16* v     = (u16*)(ws + off); off += 16777216;
  u16* vT    = (u16*)(ws + off); off += 16777216;
  u16* ql    = (u16*)(ws + off); off += 1048576;
  u16* kl    = (u16*)(ws + off); off += 1048576;
  u16* a2h   = (u16*)(ws + off); off += 4194304;
  u16* zA    = (u16*)(ws + off); off += 4194304;
  u16* zAT   = (u16*)(ws + off); off += 4194304;
  u16* zB    = (u16*)(ws + off); off += 4194304;
  u16* zBT   = (u16*)(ws + off); off += 4194304;
  u16* xz    = (u16*)(ws + off); off += 4194304;
  u16* xzT   = (u16*)(ws + off); off += 4194304;
  u16* e1T   = (u16*)(ws + off); off += 4194304;
  u16* e2T   = (u16*)(ws + off); off += 4194304;
  u16* Wm    = (u16*)(ws + off); off += 4194304;
  u16* a3vT  = (u16*)(ws + off); off += 1048576;
  u16* w2T   = (u16*)(ws + off); off += 1048576;
  u16* wqkvT = (u16*)(ws + off); off += 1572864;
  u16* woutT = (u16*)(ws + off); off += 524288;
  u16* outh  = (u16*)(ws + off); off += 16777216;
  u16* po    = (u16*)(ws + off); off += 8388608;
  float* pl  = (float*)(ws + off); off += 262144;
  float* pcs = (float*)(ws + off); off += 131072;
  unsigned* scal = (unsigned*)(ws + off); off += 8;

  prep_kernel<<<20480, 256, 0, stream>>>(x, norm_w, norm_b, xn, w_qkv, wqkvT, w_out, woutT, scal);
  qkv_mfma<<<1536, 256, 0, stream>>>(xn, wqkvT, q, k, v, ql, kl);
  mid_kernel<<<3200, 256, 0, stream>>>(v, vT, ql, kl, a2h, pcs, res_w, outh);
  fp_cm<<<544, 256, 0, stream>>>(ql, k, vT, po, pl, pcs, scal);
  merge_z0<<<8320, 256, 0, stream>>>(po, pl, a3vT, a2h, scal, zA, zAT);

  u16 *zc = zA, *zcT = zAT, *zn = zB, *znT = zBT;
  for (int it = 0; it < 6; it++) {
    pinv_s1<<<dim3(4,4,32), 256, 0, stream>>>(a2h, zcT, xz, xzT, e1T);
    pinv_s2<<<dim3(4,4,64), 256, 0, stream>>>(xz, e1T, zc, xzT, e2T, Wm);
    pinv_s3<<<dim3(4,4,32), 256, 0, stream>>>(Wm, e2T, zc, zn, znT);
    u16* tp;
    tp = zc; zc = zn; zn = tp;
    tp = zcT; zcT = znT; znT = tp;
  }

  bmm64<<<dim3(1,4,32), 256, 0, stream>>>(zc, a3vT, w2T, 256, 64, 256);
  flash_a1<<<dim3(64, 32), 256, 0, stream>>>(q, kl, w2T, outh);
  conv_unused_guard: ;
  out_mfma<<<512, 256, 0, stream>>>(outh, woutT, b_out, x, out);
}